// Round 1
// baseline (1390.744 us; speedup 1.0000x reference)
//
#include <hip/hip_runtime.h>
#include <hip/hip_bf16.h>
#include <math.h>
#include <limits.h>

#define BB 8
#define NN 50000
#define EPSF 1.1920928955078125e-07f   // float32 machine eps
#define CEPS2 1.0e-6f                  // CHAR_EPS^2

// ---- ws layout (float offsets) ----
// params: 8 batches * 16 floats = [a, invP0..3, tfirst_pos, tfirst_neg, tlast_pos, tlast_neg, pad...]
#define OFF_PARAMS 0
#define OFF_SUMS   128        // [0]=event_loss, [1]=smooth
#define OFF_ACC    256
// per-scale accumulator bases; per scale block = B(8)*pol(2)*sign(2)*arr(2)*hw = 64*hw floats
#define SB0 (OFF_ACC)
#define SB1 (SB0 + 64*1024)
#define SB2 (SB1 + 64*4096)
#define SB3 (SB2 + 64*16384)
#define WS_FLOATS (SB3 + 64*65536)     // 5,570,816 floats = 22.3 MB

__device__ __forceinline__ float block_reduce_sum(float v) {
    __shared__ float sm_[4];
    int lane = threadIdx.x & 63;
    int wid  = threadIdx.x >> 6;
    #pragma unroll
    for (int o = 32; o > 0; o >>= 1) v += __shfl_down(v, o);
    if (lane == 0) sm_[wid] = v;
    __syncthreads();
    float r = 0.0f;
    if (threadIdx.x == 0) {
        int nw = blockDim.x >> 6;
        for (int i = 0; i < nw; ++i) r += sm_[i];
    }
    return r;   // valid on thread 0 only
}

__global__ void zero_ws_kernel(float4* __restrict__ ws4) {
    const int total = WS_FLOATS / 4;
    int stride = gridDim.x * blockDim.x;
    for (int i = blockIdx.x * blockDim.x + threadIdx.x; i < total; i += stride)
        ws4[i] = make_float4(0.f, 0.f, 0.f, 0.f);
}

// one block per batch: find first/last index per polarity, compute t-normalization chain
__global__ void prep_kernel(const float* __restrict__ ev, float* __restrict__ ws) {
    int b = blockIdx.x;
    const float* t = ev + ((size_t)b * 4 + 2) * NN;
    const float* p = ev + ((size_t)b * 4 + 3) * NN;
    int tid = threadIdx.x;
    int minp = INT_MAX, maxp = -1, minn = INT_MAX, maxn = -1;
    for (int i = tid; i < NN; i += 256) {
        bool pos = (p[i] == 1.0f);
        if (pos) { if (i < minp) minp = i; if (i > maxp) maxp = i; }
        else     { if (i < minn) minn = i; if (i > maxn) maxn = i; }
    }
    __shared__ int s0[256], s1[256], s2[256], s3[256];
    s0[tid] = minp; s1[tid] = maxp; s2[tid] = minn; s3[tid] = maxn;
    __syncthreads();
    for (int o = 128; o > 0; o >>= 1) {
        if (tid < o) {
            s0[tid] = min(s0[tid], s0[tid + o]);
            s1[tid] = max(s1[tid], s1[tid + o]);
            s2[tid] = min(s2[tid], s2[tid + o]);
            s3[tid] = max(s3[tid], s3[tid + o]);
        }
        __syncthreads();
    }
    if (tid == 0) {
        int mp = s0[0], xp = s1[0], mn = s2[0], xn = s3[0];
        if (xp < 0) { mp = 0; xp = NN - 1; }   // argmax(all-false)==0 semantics
        if (xn < 0) { mn = 0; xn = NN - 1; }
        float a = t[0], tlast = t[NN - 1];
        float d0 = tlast - a + EPSF;
        float P  = d0;
        float r  = (tlast - a) / d0;
        float* pp = ws + OFF_PARAMS + b * 16;
        pp[0] = a;
        pp[1] = 1.0f / P;
        for (int i = 1; i < 4; ++i) {
            float d = r + EPSF;
            P *= d;
            r  = r / d;
            pp[1 + i] = 1.0f / P;
        }
        pp[5] = t[mp];   // first pos
        pp[6] = t[mn];   // first neg
        pp[7] = t[xp];   // last pos
        pp[8] = t[xn];   // last neg
    }
}

__global__ void scatter_kernel(const float* __restrict__ ev,
                               const float* __restrict__ f0, const float* __restrict__ f1,
                               const float* __restrict__ f2, const float* __restrict__ f3,
                               float* __restrict__ ws) {
    int gid = blockIdx.x * blockDim.x + threadIdx.x;
    if (gid >= BB * NN) return;
    int b = gid / NN, n = gid - b * NN;
    const float* eb = ev + (size_t)b * 4 * NN;
    float x = eb[n];
    float y = eb[NN + n];
    float t = eb[2 * NN + n];
    float p = eb[3 * NN + n];
    int pol = (p == 1.0f) ? 0 : 1;
    const float* pp = ws + OFF_PARAMS + b * 16;
    float a   = pp[0];
    float tfb = pp[5 + pol] - a;    // first of this polarity, offset by a
    float tlb = pp[7 + pol] - a;    // last of this polarity
    float tb  = t - a;

    const float* flows[4] = { f0, f1, f2, f3 };
    const int   wdim[4]   = { 32, 64, 128, 256 };
    const int   sbase[4]  = { SB0, SB1, SB2, SB3 };

    #pragma unroll
    for (int i = 0; i < 4; ++i) {
        int   w  = wdim[i];
        int   hw = w * w;
        float inv_scale = (float)w * (1.0f / 256.0f);   // 1/scale (exact, pow2)
        int xi = (int)(x * inv_scale);
        int yi = (int)(y * inv_scale);
        const float* fl = flows[i] + (size_t)b * 2 * hw;
        float fx = fl[yi * w + xi];
        float fy = fl[hw + yi * w + xi];
        float invP = pp[1 + i];
        float tn  = tb  * invP;
        float tN_ = tlb * invP;
        float t0_ = tfb * invP;
        #pragma unroll
        for (int s = 0; s < 2; ++s) {
            float t_ = (s == 0) ? (tN_ - tn + EPSF) : (t0_ - tn - EPSF);
            float x_ = fminf(fmaxf((float)xi + t_ * fx, 0.0f), (float)(w - 1));
            float y_ = fminf(fmaxf((float)yi + t_ * fy, 0.0f), (float)(w - 1));
            float x0 = floorf(x_), x1 = ceilf(x_);
            float y0 = floorf(y_), y1 = ceilf(y_);
            float x0r = 1.0f - (x_ - x0), x1r = 1.0f - (x1 - x_);
            float y0r = 1.0f - (y_ - y0), y1r = 1.0f - (y1 - y_);
            float* num = ws + (size_t)sbase[i] + (size_t)(((b * 2 + pol) * 2 + s) * 2) * hw;
            float* den = num + hw;
            int ix0 = (int)x0, ix1 = (int)x1;
            int iy0 = (int)y0 * w, iy1 = (int)y1 * w;
            atomicAdd(&num[iy0 + ix0], (x0r * y0r + EPSF) * t_);
            atomicAdd(&den[iy0 + ix0], 1.0f);
            atomicAdd(&num[iy0 + ix1], (x1r * y0r + EPSF) * t_);
            atomicAdd(&den[iy0 + ix1], 1.0f);
            atomicAdd(&num[iy1 + ix0], (x0r * y1r + EPSF) * t_);
            atomicAdd(&den[iy1 + ix0], 1.0f);
            atomicAdd(&num[iy1 + ix1], (x1r * y1r + EPSF) * t_);
            atomicAdd(&den[iy1 + ix1], 1.0f);
        }
    }
}

// sum over all (num/(den+eps))^2 pairs -> sums[0]
__global__ void reduce_ev_kernel(const float* __restrict__ ws, float* __restrict__ sums) {
    int stride = gridDim.x * blockDim.x;
    float acc = 0.0f;
    // pair counts per scale: 32*hw; cumulative: 32768, 163840, 688128, 2785280
    for (int j = blockIdx.x * blockDim.x + threadIdx.x; j < 2785280; j += stride) {
        int jj, lg, base;
        if (j < 32768)       { jj = j;          lg = 10; base = SB0; }
        else if (j < 163840) { jj = j - 32768;  lg = 12; base = SB1; }
        else if (j < 688128) { jj = j - 163840; lg = 14; base = SB2; }
        else                 { jj = j - 688128; lg = 16; base = SB3; }
        int hw    = 1 << lg;
        int combo = jj >> lg;
        int pix   = jj & (hw - 1);
        const float* numb = ws + base + ((size_t)combo * 2 << lg);
        float nm = numb[pix];
        float dn = numb[hw + pix];
        float v  = nm / (dn + EPSF);
        acc += v * v;
    }
    float r = block_reduce_sum(acc);
    if (threadIdx.x == 0) atomicAdd(&sums[0], r);
}

__device__ __forceinline__ float charb(float d) {
    return powf(d * d + CEPS2, 0.45f);
}

__global__ void smooth_kernel(const float* __restrict__ f0, const float* __restrict__ f1,
                              const float* __restrict__ f2, const float* __restrict__ f3,
                              float* __restrict__ sums) {
    int stride = gridDim.x * blockDim.x;
    float acc = 0.0f;
    // elems per flow: 16*hw; cumulative: 16384, 81920, 344064, 1392640
    for (int j = blockIdx.x * blockDim.x + threadIdx.x; j < 1392640; j += stride) {
        const float* F; int jj, lg, lw;
        if (j < 16384)       { F = f0; jj = j;          lg = 10; lw = 5; }
        else if (j < 81920)  { F = f1; jj = j - 16384;  lg = 12; lw = 6; }
        else if (j < 344064) { F = f2; jj = j - 81920;  lg = 14; lw = 7; }
        else                 { F = f3; jj = j - 344064; lg = 16; lw = 8; }
        int hw = 1 << lg;
        int w  = 1 << lw;
        int plane = jj >> lg;
        int pix   = jj & (hw - 1);
        int yy = pix >> lw;
        int xx = pix & (w - 1);
        const float* Fp = F + ((size_t)plane << lg);
        float v = Fp[pix];
        bool yok = (yy < w - 1);
        bool xok = (xx < w - 1);
        float inv_e = 0.5f / (16.0f * (float)(w - 1) * (float)w);         // h-dir & w-dir counts (h==w)
        float inv_d = 0.5f / (16.0f * (float)(w - 1) * (float)(w - 1));   // diagonal counts
        if (yok) { float d = Fp[pix + w] - v;          acc += charb(d) * inv_e; }
        if (xok) { float d = Fp[pix + 1] - v;          acc += charb(d) * inv_e; }
        if (yok && xok) {
            float d  = Fp[pix + w + 1] - v;            acc += charb(d)  * inv_d;
            float d2 = Fp[pix + 1] - Fp[pix + w];      acc += charb(d2) * inv_d;
        }
    }
    float r = block_reduce_sum(acc);
    if (threadIdx.x == 0) atomicAdd(&sums[1], r);
}

__global__ void finalize_kernel(const float* __restrict__ sums, float* __restrict__ out) {
    if (threadIdx.x == 0) {
        float evl = sums[0], sm = sums[1];
        out[0] = evl + sm;
        out[1] = evl;
        out[2] = sm;
    }
}

extern "C" void kernel_launch(void* const* d_in, const int* in_sizes, int n_in,
                              void* d_out, int out_size, void* d_ws, size_t ws_size,
                              hipStream_t stream) {
    const float* ev = (const float*)d_in[0];
    const float* f0 = (const float*)d_in[1];
    const float* f1 = (const float*)d_in[2];
    const float* f2 = (const float*)d_in[3];
    const float* f3 = (const float*)d_in[4];
    float* ws  = (float*)d_ws;
    float* out = (float*)d_out;

    zero_ws_kernel<<<2048, 256, 0, stream>>>((float4*)d_ws);
    prep_kernel<<<BB, 256, 0, stream>>>(ev, ws);
    scatter_kernel<<<(BB * NN + 255) / 256, 256, 0, stream>>>(ev, f0, f1, f2, f3, ws);
    reduce_ev_kernel<<<2048, 256, 0, stream>>>(ws, ws + OFF_SUMS);
    smooth_kernel<<<2048, 256, 0, stream>>>(f0, f1, f2, f3, ws + OFF_SUMS);
    finalize_kernel<<<1, 64, 0, stream>>>(ws + OFF_SUMS, out);
}

// Round 2
// 1372.625 us; speedup vs baseline: 1.0132x; 1.0132x over previous
//
#include <hip/hip_runtime.h>
#include <hip/hip_bf16.h>
#include <math.h>
#include <limits.h>

#define BB 8
#define NN 50000
#define EPSF 1.1920928955078125e-07f   // float32 machine eps
#define CEPS2 1.0e-6f                  // CHAR_EPS^2

// ---- ws layout (float offsets) ----
// params: 8 batches * 16 floats = [a, invP0..3, tfirst_pos, tfirst_neg, tlast_pos, tlast_neg, pad...]
#define OFF_PARAMS 0
#define OFF_SUMS   128        // [0]=event_loss, [1]=smooth
#define OFF_ACC    256
// per-scale accumulator bases; per scale block = B(8)*pol(2)*sign(2)*arr(2)*hw = 64*hw floats
#define SB0 (OFF_ACC)
#define SB1 (SB0 + 64*1024)
#define SB2 (SB1 + 64*4096)
#define SB3 (SB2 + 64*16384)
#define WS_FLOATS (SB3 + 64*65536)     // 5,570,816 floats = 22.3 MB

__device__ __forceinline__ float block_reduce_sum(float v) {
    __shared__ float sm_[4];
    int lane = threadIdx.x & 63;
    int wid  = threadIdx.x >> 6;
    #pragma unroll
    for (int o = 32; o > 0; o >>= 1) v += __shfl_down(v, o);
    if (lane == 0) sm_[wid] = v;
    __syncthreads();
    float r = 0.0f;
    if (threadIdx.x == 0) {
        int nw = blockDim.x >> 6;
        for (int i = 0; i < nw; ++i) r += sm_[i];
    }
    return r;   // valid on thread 0 only
}

__global__ void zero_ws_kernel(float4* __restrict__ ws4) {
    const int total = WS_FLOATS / 4;
    int stride = gridDim.x * blockDim.x;
    for (int i = blockIdx.x * blockDim.x + threadIdx.x; i < total; i += stride)
        ws4[i] = make_float4(0.f, 0.f, 0.f, 0.f);
}

// one block per batch: find first/last index per polarity, compute t-normalization chain
__global__ void prep_kernel(const float* __restrict__ ev, float* __restrict__ ws) {
    int b = blockIdx.x;
    const float* t = ev + ((size_t)b * 4 + 2) * NN;
    const float* p = ev + ((size_t)b * 4 + 3) * NN;
    int tid = threadIdx.x;
    int minp = INT_MAX, maxp = -1, minn = INT_MAX, maxn = -1;
    for (int i = tid; i < NN; i += 256) {
        bool pos = (p[i] == 1.0f);
        if (pos) { if (i < minp) minp = i; if (i > maxp) maxp = i; }
        else     { if (i < minn) minn = i; if (i > maxn) maxn = i; }
    }
    __shared__ int s0[256], s1[256], s2[256], s3[256];
    s0[tid] = minp; s1[tid] = maxp; s2[tid] = minn; s3[tid] = maxn;
    __syncthreads();
    for (int o = 128; o > 0; o >>= 1) {
        if (tid < o) {
            s0[tid] = min(s0[tid], s0[tid + o]);
            s1[tid] = max(s1[tid], s1[tid + o]);
            s2[tid] = min(s2[tid], s2[tid + o]);
            s3[tid] = max(s3[tid], s3[tid + o]);
        }
        __syncthreads();
    }
    if (tid == 0) {
        int mp = s0[0], xp = s1[0], mn = s2[0], xn = s3[0];
        if (xp < 0) { mp = 0; xp = NN - 1; }   // argmax(all-false)==0 semantics
        if (xn < 0) { mn = 0; xn = NN - 1; }
        float a = t[0], tlast = t[NN - 1];
        float d0 = tlast - a + EPSF;
        float P  = d0;
        float r  = (tlast - a) / d0;
        float* pp = ws + OFF_PARAMS + b * 16;
        pp[0] = a;
        pp[1] = 1.0f / P;
        for (int i = 1; i < 4; ++i) {
            float d = r + EPSF;
            P *= d;
            r  = r / d;
            pp[1 + i] = 1.0f / P;
        }
        pp[5] = t[mp];   // first pos
        pp[6] = t[mn];   // first neg
        pp[7] = t[xp];   // last pos
        pp[8] = t[xn];   // last neg
    }
}

// XCD-pinned: blockIdx.x % 8 == batch == XCD (MI355X round-robins consecutive
// workgroups across the 8 XCDs). Each batch's 2.78 MB accumulator slice then
// stays resident in ONE XCD's 4 MB L2 -> atomics resolve in-L2, no cross-XCD
// cacheline ping-pong through HBM.
__global__ void scatter_kernel(const float* __restrict__ ev,
                               const float* __restrict__ f0, const float* __restrict__ f1,
                               const float* __restrict__ f2, const float* __restrict__ f3,
                               float* __restrict__ ws) {
    int b = blockIdx.x & 7;
    int n = (blockIdx.x >> 3) * 256 + threadIdx.x;
    if (n >= NN) return;
    const float* eb = ev + (size_t)b * 4 * NN;
    float x = eb[n];
    float y = eb[NN + n];
    float t = eb[2 * NN + n];
    float p = eb[3 * NN + n];
    int pol = (p == 1.0f) ? 0 : 1;
    const float* pp = ws + OFF_PARAMS + b * 16;
    float a   = pp[0];
    float tfb = pp[5 + pol] - a;    // first of this polarity, offset by a
    float tlb = pp[7 + pol] - a;    // last of this polarity
    float tb  = t - a;

    const float* flows[4] = { f0, f1, f2, f3 };
    const int   wdim[4]   = { 32, 64, 128, 256 };
    const int   sbase[4]  = { SB0, SB1, SB2, SB3 };

    #pragma unroll
    for (int i = 0; i < 4; ++i) {
        int   w  = wdim[i];
        int   hw = w * w;
        float inv_scale = (float)w * (1.0f / 256.0f);   // 1/scale (exact, pow2)
        int xi = (int)(x * inv_scale);
        int yi = (int)(y * inv_scale);
        const float* fl = flows[i] + (size_t)b * 2 * hw;
        float fx = fl[yi * w + xi];
        float fy = fl[hw + yi * w + xi];
        float invP = pp[1 + i];
        float tn  = tb  * invP;
        float tN_ = tlb * invP;
        float t0_ = tfb * invP;
        #pragma unroll
        for (int s = 0; s < 2; ++s) {
            float t_ = (s == 0) ? (tN_ - tn + EPSF) : (t0_ - tn - EPSF);
            float x_ = fminf(fmaxf((float)xi + t_ * fx, 0.0f), (float)(w - 1));
            float y_ = fminf(fmaxf((float)yi + t_ * fy, 0.0f), (float)(w - 1));
            float x0 = floorf(x_), x1 = ceilf(x_);
            float y0 = floorf(y_), y1 = ceilf(y_);
            float x0r = 1.0f - (x_ - x0), x1r = 1.0f - (x1 - x_);
            float y0r = 1.0f - (y_ - y0), y1r = 1.0f - (y1 - y_);
            float* num = ws + (size_t)sbase[i] + (size_t)(((b * 2 + pol) * 2 + s) * 2) * hw;
            float* den = num + hw;
            int ix0 = (int)x0, ix1 = (int)x1;
            int iy0 = (int)y0 * w, iy1 = (int)y1 * w;
            atomicAdd(&num[iy0 + ix0], (x0r * y0r + EPSF) * t_);
            atomicAdd(&den[iy0 + ix0], 1.0f);
            atomicAdd(&num[iy0 + ix1], (x1r * y0r + EPSF) * t_);
            atomicAdd(&den[iy0 + ix1], 1.0f);
            atomicAdd(&num[iy1 + ix0], (x0r * y1r + EPSF) * t_);
            atomicAdd(&den[iy1 + ix0], 1.0f);
            atomicAdd(&num[iy1 + ix1], (x1r * y1r + EPSF) * t_);
            atomicAdd(&den[iy1 + ix1], 1.0f);
        }
    }
}

// sum over all (num/(den+eps))^2 pairs -> sums[0]
__global__ void reduce_ev_kernel(const float* __restrict__ ws, float* __restrict__ sums) {
    int stride = gridDim.x * blockDim.x;
    float acc = 0.0f;
    // pair counts per scale: 32*hw; cumulative: 32768, 163840, 688128, 2785280
    for (int j = blockIdx.x * blockDim.x + threadIdx.x; j < 2785280; j += stride) {
        int jj, lg, base;
        if (j < 32768)       { jj = j;          lg = 10; base = SB0; }
        else if (j < 163840) { jj = j - 32768;  lg = 12; base = SB1; }
        else if (j < 688128) { jj = j - 163840; lg = 14; base = SB2; }
        else                 { jj = j - 688128; lg = 16; base = SB3; }
        int hw    = 1 << lg;
        int combo = jj >> lg;
        int pix   = jj & (hw - 1);
        const float* numb = ws + base + ((size_t)combo * 2 << lg);
        float nm = numb[pix];
        float dn = numb[hw + pix];
        float v  = nm / (dn + EPSF);
        acc += v * v;
    }
    float r = block_reduce_sum(acc);
    if (threadIdx.x == 0) atomicAdd(&sums[0], r);
}

__device__ __forceinline__ float charb(float d) {
    return powf(d * d + CEPS2, 0.45f);
}

__global__ void smooth_kernel(const float* __restrict__ f0, const float* __restrict__ f1,
                              const float* __restrict__ f2, const float* __restrict__ f3,
                              float* __restrict__ sums) {
    int stride = gridDim.x * blockDim.x;
    float acc = 0.0f;
    // elems per flow: 16*hw; cumulative: 16384, 81920, 344064, 1392640
    for (int j = blockIdx.x * blockDim.x + threadIdx.x; j < 1392640; j += stride) {
        const float* F; int jj, lg, lw;
        if (j < 16384)       { F = f0; jj = j;          lg = 10; lw = 5; }
        else if (j < 81920)  { F = f1; jj = j - 16384;  lg = 12; lw = 6; }
        else if (j < 344064) { F = f2; jj = j - 81920;  lg = 14; lw = 7; }
        else                 { F = f3; jj = j - 344064; lg = 16; lw = 8; }
        int hw = 1 << lg;
        int w  = 1 << lw;
        int plane = jj >> lg;
        int pix   = jj & (hw - 1);
        int yy = pix >> lw;
        int xx = pix & (w - 1);
        const float* Fp = F + ((size_t)plane << lg);
        float v = Fp[pix];
        bool yok = (yy < w - 1);
        bool xok = (xx < w - 1);
        float inv_e = 0.5f / (16.0f * (float)(w - 1) * (float)w);         // h-dir & w-dir counts (h==w)
        float inv_d = 0.5f / (16.0f * (float)(w - 1) * (float)(w - 1));   // diagonal counts
        if (yok) { float d = Fp[pix + w] - v;          acc += charb(d) * inv_e; }
        if (xok) { float d = Fp[pix + 1] - v;          acc += charb(d) * inv_e; }
        if (yok && xok) {
            float d  = Fp[pix + w + 1] - v;            acc += charb(d)  * inv_d;
            float d2 = Fp[pix + 1] - Fp[pix + w];      acc += charb(d2) * inv_d;
        }
    }
    float r = block_reduce_sum(acc);
    if (threadIdx.x == 0) atomicAdd(&sums[1], r);
}

__global__ void finalize_kernel(const float* __restrict__ sums, float* __restrict__ out) {
    if (threadIdx.x == 0) {
        float evl = sums[0], sm = sums[1];
        out[0] = evl + sm;
        out[1] = evl;
        out[2] = sm;
    }
}

extern "C" void kernel_launch(void* const* d_in, const int* in_sizes, int n_in,
                              void* d_out, int out_size, void* d_ws, size_t ws_size,
                              hipStream_t stream) {
    const float* ev = (const float*)d_in[0];
    const float* f0 = (const float*)d_in[1];
    const float* f1 = (const float*)d_in[2];
    const float* f2 = (const float*)d_in[3];
    const float* f3 = (const float*)d_in[4];
    float* ws  = (float*)d_ws;
    float* out = (float*)d_out;

    zero_ws_kernel<<<2048, 256, 0, stream>>>((float4*)d_ws);
    prep_kernel<<<BB, 256, 0, stream>>>(ev, ws);
    scatter_kernel<<<8 * ((NN + 255) / 256), 256, 0, stream>>>(ev, f0, f1, f2, f3, ws);
    reduce_ev_kernel<<<2048, 256, 0, stream>>>(ws, ws + OFF_SUMS);
    smooth_kernel<<<2048, 256, 0, stream>>>(f0, f1, f2, f3, ws + OFF_SUMS);
    finalize_kernel<<<1, 64, 0, stream>>>(ws + OFF_SUMS, out);
}

// Round 3
// 611.126 us; speedup vs baseline: 2.2757x; 2.2461x over previous
//
#include <hip/hip_runtime.h>
#include <hip/hip_bf16.h>
#include <math.h>
#include <limits.h>

#define BB 8
#define NN 50000
#define EPSF 1.1920928955078125e-07f   // float32 machine eps
#define CEPS2 1.0e-6f                  // CHAR_EPS^2
#define QS   4194304.0f                // 2^22 fixed-point quantum for packed num
#define QINV (1.0f/4194304.0f)

// ---- ws layout ----
// floats [0..127]: params (8 batches * 16)
// floats [128..255]: sums [0]=event_loss [1]=smooth
// from float offset 256: packed u64 accumulators, 32 combos (b*4+pol*2+sign) per scale
//   scale cells (u64): s0 32*1024=32768 | s1 32*4096=131072 | s2 32*16384=524288 | s3 32*65536=2097152
#define OFF_PARAMS 0
#define OFF_SUMS   128
#define OFF_ACC    256              // float offset; 8-byte aligned
#define Q0 0
#define Q1 32768
#define Q2 163840
#define Q3 688128
#define QTOT 2785280                // total packed cells
#define WS_FLOATS (OFF_ACC + QTOT*2)

// packed encode: one 64-bit add carries den+=1 (bits 40..63) and num+=val (2^-22 fixed, bits 0..39)
__device__ __forceinline__ unsigned long long encq(float v) {
    return (unsigned long long)((1LL << 40) + (long long)__float2int_rn(v * QS));
}

__device__ __forceinline__ float block_reduce_sum(float v) {
    __shared__ float sm_[8];
    int lane = threadIdx.x & 63;
    int wid  = threadIdx.x >> 6;
    #pragma unroll
    for (int o = 32; o > 0; o >>= 1) v += __shfl_down(v, o);
    if (lane == 0) sm_[wid] = v;
    __syncthreads();
    float r = 0.0f;
    if (threadIdx.x == 0) {
        int nw = blockDim.x >> 6;
        for (int i = 0; i < nw; ++i) r += sm_[i];
    }
    return r;   // valid on thread 0 only
}

__global__ void zero_ws_kernel(float4* __restrict__ ws4) {
    const int total = WS_FLOATS / 4;
    int stride = gridDim.x * blockDim.x;
    for (int i = blockIdx.x * blockDim.x + threadIdx.x; i < total; i += stride)
        ws4[i] = make_float4(0.f, 0.f, 0.f, 0.f);
}

// one block per batch: first/last index per polarity + t-normalization chain
__global__ void prep_kernel(const float* __restrict__ ev, float* __restrict__ ws) {
    int b = blockIdx.x;
    const float* t = ev + ((size_t)b * 4 + 2) * NN;
    const float* p = ev + ((size_t)b * 4 + 3) * NN;
    int tid = threadIdx.x;
    int minp = INT_MAX, maxp = -1, minn = INT_MAX, maxn = -1;
    for (int i = tid; i < NN; i += 256) {
        bool pos = (p[i] == 1.0f);
        if (pos) { if (i < minp) minp = i; if (i > maxp) maxp = i; }
        else     { if (i < minn) minn = i; if (i > maxn) maxn = i; }
    }
    __shared__ int s0[256], s1[256], s2[256], s3[256];
    s0[tid] = minp; s1[tid] = maxp; s2[tid] = minn; s3[tid] = maxn;
    __syncthreads();
    for (int o = 128; o > 0; o >>= 1) {
        if (tid < o) {
            s0[tid] = min(s0[tid], s0[tid + o]);
            s1[tid] = max(s1[tid], s1[tid + o]);
            s2[tid] = min(s2[tid], s2[tid + o]);
            s3[tid] = max(s3[tid], s3[tid + o]);
        }
        __syncthreads();
    }
    if (tid == 0) {
        int mp = s0[0], xp = s1[0], mn = s2[0], xn = s3[0];
        if (xp < 0) { mp = 0; xp = NN - 1; }
        if (xn < 0) { mn = 0; xn = NN - 1; }
        float a = t[0], tlast = t[NN - 1];
        float d0 = tlast - a + EPSF;
        float P  = d0;
        float r  = (tlast - a) / d0;
        float* pp = ws + OFF_PARAMS + b * 16;
        pp[0] = a;
        pp[1] = 1.0f / P;
        for (int i = 1; i < 4; ++i) {
            float d = r + EPSF;
            P *= d;
            r  = r / d;
            pp[1 + i] = 1.0f / P;
        }
        pp[5] = t[mp];   // first pos
        pp[6] = t[mn];   // first neg
        pp[7] = t[xp];   // last pos
        pp[8] = t[xn];   // last neg
    }
}

// grid = 8 batches (XCD-pinned via blockIdx&7) x 32 chunks, 512 threads.
// Scale 0 privatized in LDS (4 combos x 1024 cells x u64 = 32 KB), scales 1-3
// use direct packed global atomics (1 u64 atomic per corner instead of 2 f32).
__global__ __launch_bounds__(512) void scatter_kernel(const float* __restrict__ ev,
                               const float* __restrict__ f0, const float* __restrict__ f1,
                               const float* __restrict__ f2, const float* __restrict__ f3,
                               float* __restrict__ ws) {
    __shared__ unsigned long long lacc[4096];
    int b = blockIdx.x & 7;
    int chunk = blockIdx.x >> 3;
    for (int i = threadIdx.x; i < 4096; i += 512) lacc[i] = 0ULL;
    __syncthreads();

    unsigned long long* qacc = (unsigned long long*)(ws + OFF_ACC);
    const float* pp = ws + OFF_PARAMS + b * 16;
    float a    = pp[0];
    float invP0 = pp[1], invP1 = pp[2], invP2 = pp[3], invP3 = pp[4];
    float tf_p = pp[5] - a, tf_n = pp[6] - a;   // first of polarity
    float tl_p = pp[7] - a, tl_n = pp[8] - a;   // last of polarity

    const float* eb = ev + (size_t)b * 4 * NN;
    const float* flows[4] = { f0, f1, f2, f3 };
    const float invPs[4]  = { invP0, invP1, invP2, invP3 };
    const int   wdim[4]   = { 32, 64, 128, 256 };
    const int   qb[4]     = { Q0, Q1, Q2, Q3 };

    for (int n = chunk * 512 + threadIdx.x; n < NN; n += 32 * 512) {
        float x = eb[n];
        float y = eb[NN + n];
        float t = eb[2 * NN + n];
        float p = eb[3 * NN + n];
        int pol = (p == 1.0f) ? 0 : 1;
        float tfb = (pol == 0) ? tf_p : tf_n;
        float tlb = (pol == 0) ? tl_p : tl_n;
        float tb  = t - a;

        #pragma unroll
        for (int i = 0; i < 4; ++i) {
            int   w  = wdim[i];
            int   hw = w * w;
            float inv_scale = (float)w * (1.0f / 256.0f);
            int xi = (int)(x * inv_scale);
            int yi = (int)(y * inv_scale);
            const float* fl = flows[i] + (size_t)b * 2 * hw;
            float fx = fl[yi * w + xi];
            float fy = fl[hw + yi * w + xi];
            float invP = invPs[i];
            float tn  = tb  * invP;
            float tN_ = tlb * invP;
            float t0_ = tfb * invP;
            #pragma unroll
            for (int s = 0; s < 2; ++s) {
                float t_ = (s == 0) ? (tN_ - tn + EPSF) : (t0_ - tn - EPSF);
                float x_ = fminf(fmaxf((float)xi + t_ * fx, 0.0f), (float)(w - 1));
                float y_ = fminf(fmaxf((float)yi + t_ * fy, 0.0f), (float)(w - 1));
                float x0 = floorf(x_), x1 = ceilf(x_);
                float y0 = floorf(y_), y1 = ceilf(y_);
                float x0r = 1.0f - (x_ - x0), x1r = 1.0f - (x1 - x_);
                float y0r = 1.0f - (y_ - y0), y1r = 1.0f - (y1 - y_);
                int ix0 = (int)x0, ix1 = (int)x1;
                int iy0 = (int)y0 * w, iy1 = (int)y1 * w;
                if (i == 0) {
                    unsigned long long* dst = lacc + (pol * 2 + s) * 1024;
                    atomicAdd(&dst[iy0 + ix0], encq((x0r * y0r + EPSF) * t_));
                    atomicAdd(&dst[iy0 + ix1], encq((x1r * y0r + EPSF) * t_));
                    atomicAdd(&dst[iy1 + ix0], encq((x0r * y1r + EPSF) * t_));
                    atomicAdd(&dst[iy1 + ix1], encq((x1r * y1r + EPSF) * t_));
                } else {
                    unsigned long long* dst = qacc + qb[i] + (size_t)(b * 4 + pol * 2 + s) * hw;
                    atomicAdd(&dst[iy0 + ix0], encq((x0r * y0r + EPSF) * t_));
                    atomicAdd(&dst[iy0 + ix1], encq((x1r * y0r + EPSF) * t_));
                    atomicAdd(&dst[iy1 + ix0], encq((x0r * y1r + EPSF) * t_));
                    atomicAdd(&dst[iy1 + ix1], encq((x1r * y1r + EPSF) * t_));
                }
            }
        }
    }
    __syncthreads();
    // flush privatized scale-0 tiles (combo*1024+cell == i, global combo = b*4+combo)
    for (int i = threadIdx.x; i < 4096; i += 512) {
        unsigned long long v = lacc[i];
        if (v) atomicAdd(&qacc[Q0 + b * 4096 + i], v);
    }
}

// sum over all packed cells of (num/(den+eps))^2 -> sums[0]
__global__ void reduce_ev_kernel(const float* __restrict__ ws, float* __restrict__ sums) {
    const unsigned long long* qacc = (const unsigned long long*)(ws + OFF_ACC);
    int stride = gridDim.x * blockDim.x;
    float acc = 0.0f;
    for (int j = blockIdx.x * blockDim.x + threadIdx.x; j < QTOT; j += stride) {
        unsigned long long A = qacc[j];
        if (!A) continue;
        unsigned long long cnt = (A + (1ULL << 39)) >> 40;
        long long sq = (long long)(A - (cnt << 40));
        float num = (float)sq * QINV;
        float den = (float)cnt;
        float v = num / (den + EPSF);
        acc += v * v;
    }
    float r = block_reduce_sum(acc);
    if (threadIdx.x == 0) atomicAdd(&sums[0], r);
}

__device__ __forceinline__ float charb(float d) {
    return powf(d * d + CEPS2, 0.45f);
}

__global__ void smooth_kernel(const float* __restrict__ f0, const float* __restrict__ f1,
                              const float* __restrict__ f2, const float* __restrict__ f3,
                              float* __restrict__ sums) {
    int stride = gridDim.x * blockDim.x;
    float acc = 0.0f;
    for (int j = blockIdx.x * blockDim.x + threadIdx.x; j < 1392640; j += stride) {
        const float* F; int jj, lg, lw;
        if (j < 16384)       { F = f0; jj = j;          lg = 10; lw = 5; }
        else if (j < 81920)  { F = f1; jj = j - 16384;  lg = 12; lw = 6; }
        else if (j < 344064) { F = f2; jj = j - 81920;  lg = 14; lw = 7; }
        else                 { F = f3; jj = j - 344064; lg = 16; lw = 8; }
        int hw = 1 << lg;
        int w  = 1 << lw;
        int plane = jj >> lg;
        int pix   = jj & (hw - 1);
        int yy = pix >> lw;
        int xx = pix & (w - 1);
        const float* Fp = F + ((size_t)plane << lg);
        float v = Fp[pix];
        bool yok = (yy < w - 1);
        bool xok = (xx < w - 1);
        float inv_e = 0.5f / (16.0f * (float)(w - 1) * (float)w);
        float inv_d = 0.5f / (16.0f * (float)(w - 1) * (float)(w - 1));
        if (yok) { float d = Fp[pix + w] - v;          acc += charb(d) * inv_e; }
        if (xok) { float d = Fp[pix + 1] - v;          acc += charb(d) * inv_e; }
        if (yok && xok) {
            float d  = Fp[pix + w + 1] - v;            acc += charb(d)  * inv_d;
            float d2 = Fp[pix + 1] - Fp[pix + w];      acc += charb(d2) * inv_d;
        }
    }
    float r = block_reduce_sum(acc);
    if (threadIdx.x == 0) atomicAdd(&sums[1], r);
}

__global__ void finalize_kernel(const float* __restrict__ sums, float* __restrict__ out) {
    if (threadIdx.x == 0) {
        float evl = sums[0], sm = sums[1];
        out[0] = evl + sm;
        out[1] = evl;
        out[2] = sm;
    }
}

extern "C" void kernel_launch(void* const* d_in, const int* in_sizes, int n_in,
                              void* d_out, int out_size, void* d_ws, size_t ws_size,
                              hipStream_t stream) {
    const float* ev = (const float*)d_in[0];
    const float* f0 = (const float*)d_in[1];
    const float* f1 = (const float*)d_in[2];
    const float* f2 = (const float*)d_in[3];
    const float* f3 = (const float*)d_in[4];
    float* ws  = (float*)d_ws;
    float* out = (float*)d_out;

    zero_ws_kernel<<<2048, 256, 0, stream>>>((float4*)d_ws);
    prep_kernel<<<BB, 256, 0, stream>>>(ev, ws);
    scatter_kernel<<<8 * 32, 512, 0, stream>>>(ev, f0, f1, f2, f3, ws);
    reduce_ev_kernel<<<2048, 256, 0, stream>>>(ws, ws + OFF_SUMS);
    smooth_kernel<<<2048, 256, 0, stream>>>(f0, f1, f2, f3, ws + OFF_SUMS);
    finalize_kernel<<<1, 64, 0, stream>>>(ws + OFF_SUMS, out);
}

// Round 4
// 308.845 us; speedup vs baseline: 4.5031x; 1.9787x over previous
//
#include <hip/hip_runtime.h>
#include <hip/hip_bf16.h>
#include <math.h>
#include <limits.h>

#define BB 8
#define NN 50000
#define EPSF 1.1920928955078125e-07f   // float32 machine eps
#define CEPS2 1.0e-6f                  // CHAR_EPS^2
#define QS   4194304.0f                // 2^22 fixed-point quantum for packed num
#define QINV (1.0f/4194304.0f)

// ---- ws layout ----
// floats [0..127]: params (8 batches * 16) = [a, invP0..3, tf_pos, tf_neg, tl_pos, tl_neg, ...]
// floats [128..255]: sums [0]=event_loss [1]=smooth   (zeroed by prep_kernel)
// float offset 256 onward: packed u64 accumulators, combo = b*4+pol*2+s per scale.
// Every u64 cell is written exactly once by its owner block (plain store) -> no zeroing.
#define OFF_PARAMS 0
#define OFF_SUMS   128
#define OFF_ACC    256              // float offset; 8-byte aligned
#define Q0 0
#define Q1 32768
#define Q2 163840
#define Q3 688128
#define QTOT 2785280                // total packed cells (u64)

// packed encode: one 64-bit add carries den+=1 (bits 40..63) and num+=val (2^-22 fixed, bits 0..39)
__device__ __forceinline__ unsigned long long encq(float v) {
    return (unsigned long long)((1LL << 40) + (long long)__float2int_rn(v * QS));
}

__device__ __forceinline__ float block_reduce_sum(float v) {
    __shared__ float sm_[8];
    int lane = threadIdx.x & 63;
    int wid  = threadIdx.x >> 6;
    #pragma unroll
    for (int o = 32; o > 0; o >>= 1) v += __shfl_down(v, o);
    if (lane == 0) sm_[wid] = v;
    __syncthreads();
    float r = 0.0f;
    if (threadIdx.x == 0) {
        int nw = blockDim.x >> 6;
        for (int i = 0; i < nw; ++i) r += sm_[i];
    }
    return r;   // valid on thread 0 only
}

// one block per batch, 1024 threads: first/last index per polarity + t-normalization chain
__global__ __launch_bounds__(1024) void prep_kernel(const float* __restrict__ ev, float* __restrict__ ws) {
    int b = blockIdx.x, tid = threadIdx.x;
    const float* t = ev + ((size_t)b * 4 + 2) * NN;
    const float4* p4 = (const float4*)(ev + ((size_t)b * 4 + 3) * NN);
    int minp = INT_MAX, maxp = -1, minn = INT_MAX, maxn = -1;
    for (int v = tid; v < NN / 4; v += 1024) {
        float4 pv = p4[v];
        int i0 = 4 * v;
        if (pv.x == 1.0f) { minp = min(minp, i0);     maxp = max(maxp, i0);     }
        else              { minn = min(minn, i0);     maxn = max(maxn, i0);     }
        if (pv.y == 1.0f) { minp = min(minp, i0 + 1); maxp = max(maxp, i0 + 1); }
        else              { minn = min(minn, i0 + 1); maxn = max(maxn, i0 + 1); }
        if (pv.z == 1.0f) { minp = min(minp, i0 + 2); maxp = max(maxp, i0 + 2); }
        else              { minn = min(minn, i0 + 2); maxn = max(maxn, i0 + 2); }
        if (pv.w == 1.0f) { minp = min(minp, i0 + 3); maxp = max(maxp, i0 + 3); }
        else              { minn = min(minn, i0 + 3); maxn = max(maxn, i0 + 3); }
    }
    __shared__ int s0[1024], s1[1024], s2[1024], s3[1024];
    s0[tid] = minp; s1[tid] = maxp; s2[tid] = minn; s3[tid] = maxn;
    __syncthreads();
    for (int o = 512; o > 0; o >>= 1) {
        if (tid < o) {
            s0[tid] = min(s0[tid], s0[tid + o]);
            s1[tid] = max(s1[tid], s1[tid + o]);
            s2[tid] = min(s2[tid], s2[tid + o]);
            s3[tid] = max(s3[tid], s3[tid + o]);
        }
        __syncthreads();
    }
    if (tid == 0) {
        int mp = s0[0], xp = s1[0], mn = s2[0], xn = s3[0];
        if (xp < 0) { mp = 0; xp = NN - 1; }   // argmax(all-false)==0 semantics
        if (xn < 0) { mn = 0; xn = NN - 1; }
        float a = t[0], tlast = t[NN - 1];
        float d0 = tlast - a + EPSF;
        float P  = d0;
        float r  = (tlast - a) / d0;
        float* pp = ws + OFF_PARAMS + b * 16;
        pp[0] = a;
        pp[1] = 1.0f / P;
        for (int i = 1; i < 4; ++i) {
            float d = r + EPSF;
            P *= d;
            r  = r / d;
            pp[1 + i] = 1.0f / P;
        }
        pp[5] = t[mp];   // first pos
        pp[6] = t[mn];   // first neg
        pp[7] = t[xp];   // last pos
        pp[8] = t[xn];   // last neg
        if (b == 0) { ws[OFF_SUMS] = 0.0f; ws[OFF_SUMS + 1] = 0.0f; }
    }
}

// Disjoint-ownership scatter: each block owns ONE (batch,pol,sign,scale,y-band)
// tile, privatized in <=64KB LDS. It scans ALL events of its batch, LDS-atomic-
// accumulates corners whose row is in its band, then plain-stores the tile
// (each qacc cell written exactly once device-wide -> no global atomics, no zeroing).
// Grid (416 blocks):
//   [0,32):    scale0, combo=bi,          full 32x32 plane       (1024 cells,  8KB)
//   [32,96):   scale1, combo=g>>1,        y-half (32 rows x64)   (2048 cells, 16KB)
//   [96,160):  scale2, combo=g>>1,        y-half (64 rows x128)  (8192 cells, 64KB)
//   [160,416): scale3, combo=g>>3,        y-band (32 rows x256)  (8192 cells, 64KB)
__global__ __launch_bounds__(512) void scatter_kernel(const float* __restrict__ ev,
                               const float* __restrict__ f0, const float* __restrict__ f1,
                               const float* __restrict__ f2, const float* __restrict__ f3,
                               float* __restrict__ ws) {
    __shared__ unsigned long long lds[8192];   // 64 KB
    unsigned long long* qacc = (unsigned long long*)(ws + OFF_ACC);

    int bi = blockIdx.x;
    int scale, combo, lo, nrows, w, hw, qb;
    const float* fl;
    if (bi < 32) {
        scale = 0; combo = bi;               lo = 0;                    nrows = 32; w = 32;  hw = 1024;  qb = Q0; fl = f0;
    } else if (bi < 96) {
        int g = bi - 32;
        scale = 1; combo = g >> 1;           lo = (g & 1) * 32;         nrows = 32; w = 64;  hw = 4096;  qb = Q1; fl = f1;
    } else if (bi < 160) {
        int g = bi - 96;
        scale = 2; combo = g >> 1;           lo = (g & 1) * 64;         nrows = 64; w = 128; hw = 16384; qb = Q2; fl = f2;
    } else {
        int g = bi - 160;
        scale = 3; combo = g >> 3;           lo = (g & 7) * 32;         nrows = 32; w = 256; hw = 65536; qb = Q3; fl = f3;
    }
    int ncell = nrows * w;
    int b   = combo >> 2;
    int pol = (combo >> 1) & 1;
    int s   = combo & 1;

    for (int i = threadIdx.x; i < ncell; i += 512) lds[i] = 0ULL;
    __syncthreads();

    const float* pp = ws + OFF_PARAMS + b * 16;
    float a    = pp[0];
    float invP = pp[1 + scale];
    float tfb  = pp[5 + pol] - a;
    float tlb  = pp[7 + pol] - a;
    float tN_  = tlb * invP;
    float t0_  = tfb * invP;
    fl += (size_t)b * 2 * hw;

    const float* ex = ev + (size_t)b * 4 * NN;
    const float* ey = ex + NN;
    const float* et = ex + 2 * NN;
    const float* ep = ex + 3 * NN;
    float inv_scale = (float)w * (1.0f / 256.0f);
    float wm1 = (float)(w - 1);

    for (int n = threadIdx.x; n < NN; n += 512) {
        float p = ep[n];
        bool match = (pol == 0) ? (p == 1.0f) : (p != 1.0f);
        if (!match) continue;
        float x = ex[n], y = ey[n], t = et[n];
        int xi = (int)(x * inv_scale);
        int yi = (int)(y * inv_scale);
        float fx = fl[yi * w + xi];
        float fy = fl[hw + yi * w + xi];
        float tn = (t - a) * invP;
        float t_ = (s == 0) ? (tN_ - tn + EPSF) : (t0_ - tn - EPSF);
        float x_ = fminf(fmaxf((float)xi + t_ * fx, 0.0f), wm1);
        float y_ = fminf(fmaxf((float)yi + t_ * fy, 0.0f), wm1);
        float x0 = floorf(x_), x1 = ceilf(x_);
        float y0 = floorf(y_), y1 = ceilf(y_);
        float x0r = 1.0f - (x_ - x0), x1r = 1.0f - (x1 - x_);
        float y0r = 1.0f - (y_ - y0), y1r = 1.0f - (y1 - y_);
        int ix0 = (int)x0, ix1 = (int)x1;
        int rr0 = (int)y0 - lo, rr1 = (int)y1 - lo;
        if (rr0 >= 0 && rr0 < nrows) {
            atomicAdd(&lds[rr0 * w + ix0], encq((x0r * y0r + EPSF) * t_));
            atomicAdd(&lds[rr0 * w + ix1], encq((x1r * y0r + EPSF) * t_));
        }
        if (rr1 >= 0 && rr1 < nrows) {
            atomicAdd(&lds[rr1 * w + ix0], encq((x0r * y1r + EPSF) * t_));
            atomicAdd(&lds[rr1 * w + ix1], encq((x1r * y1r + EPSF) * t_));
        }
    }
    __syncthreads();
    unsigned long long* dst = qacc + qb + (size_t)combo * hw + (size_t)lo * w;
    for (int i = threadIdx.x; i < ncell; i += 512) dst[i] = lds[i];
}

// sum over all packed cells of (num/(den+eps))^2 -> sums[0]
__global__ void reduce_ev_kernel(const float* __restrict__ ws, float* __restrict__ sums) {
    const unsigned long long* qacc = (const unsigned long long*)(ws + OFF_ACC);
    int stride = gridDim.x * blockDim.x;
    float acc = 0.0f;
    for (int j = blockIdx.x * blockDim.x + threadIdx.x; j < QTOT; j += stride) {
        unsigned long long A = qacc[j];
        if (!A) continue;
        unsigned long long cnt = (A + (1ULL << 39)) >> 40;
        long long sq = (long long)(A - (cnt << 40));
        float num = (float)sq * QINV;
        float den = (float)cnt;
        float v = num / (den + EPSF);
        acc += v * v;
    }
    float r = block_reduce_sum(acc);
    if (threadIdx.x == 0) atomicAdd(&sums[0], r);
}

__device__ __forceinline__ float charb(float d) {
    return powf(d * d + CEPS2, 0.45f);
}

__global__ void smooth_kernel(const float* __restrict__ f0, const float* __restrict__ f1,
                              const float* __restrict__ f2, const float* __restrict__ f3,
                              float* __restrict__ sums) {
    int stride = gridDim.x * blockDim.x;
    float acc = 0.0f;
    for (int j = blockIdx.x * blockDim.x + threadIdx.x; j < 1392640; j += stride) {
        const float* F; int jj, lg, lw;
        if (j < 16384)       { F = f0; jj = j;          lg = 10; lw = 5; }
        else if (j < 81920)  { F = f1; jj = j - 16384;  lg = 12; lw = 6; }
        else if (j < 344064) { F = f2; jj = j - 81920;  lg = 14; lw = 7; }
        else                 { F = f3; jj = j - 344064; lg = 16; lw = 8; }
        int hw = 1 << lg;
        int w  = 1 << lw;
        int plane = jj >> lg;
        int pix   = jj & (hw - 1);
        int yy = pix >> lw;
        int xx = pix & (w - 1);
        const float* Fp = F + ((size_t)plane << lg);
        float v = Fp[pix];
        bool yok = (yy < w - 1);
        bool xok = (xx < w - 1);
        float inv_e = 0.5f / (16.0f * (float)(w - 1) * (float)w);
        float inv_d = 0.5f / (16.0f * (float)(w - 1) * (float)(w - 1));
        if (yok) { float d = Fp[pix + w] - v;          acc += charb(d) * inv_e; }
        if (xok) { float d = Fp[pix + 1] - v;          acc += charb(d) * inv_e; }
        if (yok && xok) {
            float d  = Fp[pix + w + 1] - v;            acc += charb(d)  * inv_d;
            float d2 = Fp[pix + 1] - Fp[pix + w];      acc += charb(d2) * inv_d;
        }
    }
    float r = block_reduce_sum(acc);
    if (threadIdx.x == 0) atomicAdd(&sums[1], r);
}

__global__ void finalize_kernel(const float* __restrict__ sums, float* __restrict__ out) {
    if (threadIdx.x == 0) {
        float evl = sums[0], sm = sums[1];
        out[0] = evl + sm;
        out[1] = evl;
        out[2] = sm;
    }
}

extern "C" void kernel_launch(void* const* d_in, const int* in_sizes, int n_in,
                              void* d_out, int out_size, void* d_ws, size_t ws_size,
                              hipStream_t stream) {
    const float* ev = (const float*)d_in[0];
    const float* f0 = (const float*)d_in[1];
    const float* f1 = (const float*)d_in[2];
    const float* f2 = (const float*)d_in[3];
    const float* f3 = (const float*)d_in[4];
    float* ws  = (float*)d_ws;
    float* out = (float*)d_out;

    prep_kernel<<<BB, 1024, 0, stream>>>(ev, ws);
    scatter_kernel<<<416, 512, 0, stream>>>(ev, f0, f1, f2, f3, ws);
    reduce_ev_kernel<<<2048, 256, 0, stream>>>(ws, ws + OFF_SUMS);
    smooth_kernel<<<2048, 256, 0, stream>>>(f0, f1, f2, f3, ws + OFF_SUMS);
    finalize_kernel<<<1, 64, 0, stream>>>(ws + OFF_SUMS, out);
}

// Round 7
// 218.506 us; speedup vs baseline: 6.3648x; 1.4134x over previous
//
#include <hip/hip_runtime.h>
#include <hip/hip_bf16.h>
#include <math.h>
#include <limits.h>

#define BB 8
#define NN 50000
#define EPSF 1.1920928955078125e-07f   // float32 machine eps
#define CEPS2 1.0e-6f                  // CHAR_EPS^2
#define QS   4194304.0f                // 2^22 fixed-point quantum for packed num
#define QINV (1.0f/4194304.0f)

// ---- ws layout (total ~3.2 MB; rounds 3-4 proved >=22.3 MB is safe) ----
// floats [0..127]: params (8 batches * 16) = [a, invP0..3, tf_pos, tf_neg, tl_pos, tl_neg, ...]
// floats [128..255]: sums [0]=event_loss [1]=smooth [2]=completion counter (prep zeroes)
// floats [256..): digest, 8B/event {f32 tb = t-t[0]; u8 x; u8 y; u8 pol} as uint2
#define OFF_PARAMS 0
#define OFF_SUMS   128
#define OFF_DG     256

#define TAIL_BLOCKS 1024
#define SMOOTH_N    1392640

// packed encode: one 64-bit add carries den+=1 (bits 40..63) and num+=val (2^-22 fixed, bits 0..39)
__device__ __forceinline__ unsigned long long encq(float v) {
    return (unsigned long long)((1LL << 40) + (long long)__float2int_rn(v * QS));
}

// valid on thread 0 only; works for blockDim 256..1024
__device__ __forceinline__ float block_reduce_sum(float v) {
    __shared__ float sm_[16];
    int lane = threadIdx.x & 63;
    int wid  = threadIdx.x >> 6;
    #pragma unroll
    for (int o = 32; o > 0; o >>= 1) v += __shfl_down(v, o);
    if (lane == 0) sm_[wid] = v;
    __syncthreads();
    float r = 0.0f;
    if (threadIdx.x == 0) {
        int nw = blockDim.x >> 6;
        for (int i = 0; i < nw; ++i) r += sm_[i];
    }
    return r;
}

// one block per batch, 1024 threads: first/last index per polarity + t-normalization chain
__global__ __launch_bounds__(1024) void prep_kernel(const float* __restrict__ ev, float* __restrict__ ws) {
    int b = blockIdx.x, tid = threadIdx.x;
    const float* t = ev + ((size_t)b * 4 + 2) * NN;
    const float4* p4 = (const float4*)(ev + ((size_t)b * 4 + 3) * NN);
    int minp = INT_MAX, maxp = -1, minn = INT_MAX, maxn = -1;
    for (int v = tid; v < NN / 4; v += 1024) {
        float4 pv = p4[v];
        int i0 = 4 * v;
        if (pv.x == 1.0f) { minp = min(minp, i0);     maxp = max(maxp, i0);     }
        else              { minn = min(minn, i0);     maxn = max(maxn, i0);     }
        if (pv.y == 1.0f) { minp = min(minp, i0 + 1); maxp = max(maxp, i0 + 1); }
        else              { minn = min(minn, i0 + 1); maxn = max(maxn, i0 + 1); }
        if (pv.z == 1.0f) { minp = min(minp, i0 + 2); maxp = max(maxp, i0 + 2); }
        else              { minn = min(minn, i0 + 2); maxn = max(maxn, i0 + 2); }
        if (pv.w == 1.0f) { minp = min(minp, i0 + 3); maxp = max(maxp, i0 + 3); }
        else              { minn = min(minn, i0 + 3); maxn = max(maxn, i0 + 3); }
    }
    __shared__ int s0[1024], s1[1024], s2[1024], s3[1024];
    s0[tid] = minp; s1[tid] = maxp; s2[tid] = minn; s3[tid] = maxn;
    __syncthreads();
    for (int o = 512; o > 0; o >>= 1) {
        if (tid < o) {
            s0[tid] = min(s0[tid], s0[tid + o]);
            s1[tid] = max(s1[tid], s1[tid + o]);
            s2[tid] = min(s2[tid], s2[tid + o]);
            s3[tid] = max(s3[tid], s3[tid + o]);
        }
        __syncthreads();
    }
    if (tid == 0) {
        int mp = s0[0], xp = s1[0], mn = s2[0], xn = s3[0];
        if (xp < 0) { mp = 0; xp = NN - 1; }   // argmax(all-false)==0 semantics
        if (xn < 0) { mn = 0; xn = NN - 1; }
        float a = t[0], tlast = t[NN - 1];
        float d0 = tlast - a + EPSF;
        float P  = d0;
        float r  = (tlast - a) / d0;
        float* pp = ws + OFF_PARAMS + b * 16;
        pp[0] = a;
        pp[1] = 1.0f / P;
        for (int i = 1; i < 4; ++i) {
            float d = r + EPSF;
            P *= d;
            r  = r / d;
            pp[1 + i] = 1.0f / P;
        }
        pp[5] = t[mp];   // first pos
        pp[6] = t[mn];   // first neg
        pp[7] = t[xp];   // last pos
        pp[8] = t[xn];   // last neg
        if (b == 0) { ws[OFF_SUMS] = 0.0f; ws[OFF_SUMS + 1] = 0.0f; ws[OFF_SUMS + 2] = 0.0f; }
    }
}

// pack events to 8B digest: {f32 tb = t - t[0]; u8 x; u8 y; u8 pol}
__global__ void digest_kernel(const float* __restrict__ ev, float* __restrict__ ws) {
    int gid = blockIdx.x * 256 + threadIdx.x;
    if (gid >= BB * NN) return;
    int b = gid / NN, n = gid - b * NN;
    const float* eb = ev + (size_t)b * 4 * NN;
    float x = eb[n];
    float y = eb[NN + n];
    float t = eb[2 * NN + n];
    float p = eb[3 * NN + n];
    float a = eb[2 * NN];          // t[0] of this batch (uniform, cached)
    uint2 d;
    d.x = __float_as_uint(t - a);
    d.y = (unsigned)(int)x | ((unsigned)(int)y << 8) | ((p == 1.0f ? 0u : 1u) << 16);
    ((uint2*)(ws + OFF_DG))[gid] = d;
}

// Disjoint-ownership scatter + fused reduce, XCD-pinned: batch = blockIdx&7,
// tile = blockIdx>>3 in [0,56). Each tile = (scale, pol, sign, y-band);
// accumulator lives ONLY in LDS; after accumulation the block decodes its own
// cells, reduces sum((num/(den+eps))^2) and atomicAdds ONE float to sums[0].
// No global accumulator exists at all.
// tiles: [0,4) s0 full plane | [4,8) s1 full | [8,24) s2 4 bands x32rows | [24,56) s3 8 bands x32rows
__global__ __launch_bounds__(1024) void scatter_kernel(const float* __restrict__ f0,
                               const float* __restrict__ f1, const float* __restrict__ f2,
                               const float* __restrict__ f3, float* __restrict__ ws) {
    __shared__ unsigned long long lds[8192];   // 64 KB max (s2/s3 bands)

    int b    = blockIdx.x & 7;
    int tile = blockIdx.x >> 3;
    int scale, c4, lo, nrows, w, sh;
    const float* fl;
    if (tile < 4)       { scale = 0; c4 = tile;      lo = 0;             nrows = 32; w = 32;  sh = 3; fl = f0; }
    else if (tile < 8)  { scale = 1; c4 = tile - 4;  lo = 0;             nrows = 64; w = 64;  sh = 2; fl = f1; }
    else if (tile < 24) { int g = tile - 8;  scale = 2; c4 = g >> 2; lo = (g & 3) * 32; nrows = 32; w = 128; sh = 1; fl = f2; }
    else                { int g = tile - 24; scale = 3; c4 = g >> 3; lo = (g & 7) * 32; nrows = 32; w = 256; sh = 0; fl = f3; }
    int pol = c4 >> 1, sgn = c4 & 1;
    int hw = w * w;
    int ncell = nrows * w;

    for (int i = threadIdx.x; i < ncell / 2; i += 1024)
        ((ulonglong2*)lds)[i] = make_ulonglong2(0ULL, 0ULL);
    __syncthreads();

    const float* pp = ws + OFF_PARAMS + b * 16;
    float a    = pp[0];
    float invP = pp[1 + scale];
    // t_ = base_t - tb*invP  (sign0: tl*invP + EPS; sign1: tf*invP - EPS)
    float edge = (sgn == 0) ? (pp[7 + pol] - a) : (pp[5 + pol] - a);
    float base_t = edge * invP + ((sgn == 0) ? EPSF : -EPSF);
    fl += (size_t)b * 2 * hw;

    const uint2* dg = ((const uint2*)(ws + OFF_DG)) + (size_t)b * NN;
    float wm1 = (float)(w - 1);

    for (int n = threadIdx.x; n < NN; n += 1024) {
        uint2 d = dg[n];
        if ((int)((d.y >> 16) & 1u) != pol) continue;
        float tb = __uint_as_float(d.x);
        int xi = (int)(d.y & 255u) >> sh;
        int yi = (int)((d.y >> 8) & 255u) >> sh;
        float fx = fl[yi * w + xi];
        float fy = fl[hw + yi * w + xi];
        float t_ = base_t - tb * invP;
        float x_ = fminf(fmaxf((float)xi + t_ * fx, 0.0f), wm1);
        float y_ = fminf(fmaxf((float)yi + t_ * fy, 0.0f), wm1);
        float x0 = floorf(x_), x1 = ceilf(x_);
        float y0 = floorf(y_), y1 = ceilf(y_);
        float x0r = 1.0f - (x_ - x0), x1r = 1.0f - (x1 - x_);
        float y0r = 1.0f - (y_ - y0), y1r = 1.0f - (y1 - y_);
        int ix0 = (int)x0, ix1 = (int)x1;
        int rr0 = (int)y0 - lo, rr1 = (int)y1 - lo;
        if (rr0 >= 0 && rr0 < nrows) {
            atomicAdd(&lds[rr0 * w + ix0], encq((x0r * y0r + EPSF) * t_));
            atomicAdd(&lds[rr0 * w + ix1], encq((x1r * y0r + EPSF) * t_));
        }
        if (rr1 >= 0 && rr1 < nrows) {
            atomicAdd(&lds[rr1 * w + ix0], encq((x0r * y1r + EPSF) * t_));
            atomicAdd(&lds[rr1 * w + ix1], encq((x1r * y1r + EPSF) * t_));
        }
    }
    __syncthreads();

    // fused reduce: decode own cells, sum (num/(den+eps))^2, one atomic out
    float acc = 0.0f;
    for (int i = threadIdx.x; i < ncell; i += 1024) {
        unsigned long long A = lds[i];
        if (!A) continue;
        unsigned long long cnt = (A + (1ULL << 39)) >> 40;
        long long sq = (long long)(A - (cnt << 40));
        float num = (float)sq * QINV;
        float v = num / ((float)cnt + EPSF);
        acc += v * v;
    }
    float r = block_reduce_sum(acc);
    if (threadIdx.x == 0) atomicAdd(ws + OFF_SUMS, r);
}

__device__ __forceinline__ float charb_fast(float d) {
    return __expf(0.45f * __logf(d * d + CEPS2));
}

// tail: smoothness only; last block (device counter) writes the 3 outputs.
// sums[0] (event loss) is complete before this dispatch starts (stream order).
__global__ void tail_kernel(const float* __restrict__ f0, const float* __restrict__ f1,
                            const float* __restrict__ f2, const float* __restrict__ f3,
                            float* __restrict__ sums, float* __restrict__ out) {
    float acc = 0.0f;
    int stride = TAIL_BLOCKS * 256;
    for (int j = blockIdx.x * 256 + threadIdx.x; j < SMOOTH_N; j += stride) {
        const float* F; int jj, lg, lw;
        if (j < 16384)       { F = f0; jj = j;          lg = 10; lw = 5; }
        else if (j < 81920)  { F = f1; jj = j - 16384;  lg = 12; lw = 6; }
        else if (j < 344064) { F = f2; jj = j - 81920;  lg = 14; lw = 7; }
        else                 { F = f3; jj = j - 344064; lg = 16; lw = 8; }
        int hw = 1 << lg;
        int w  = 1 << lw;
        int plane = jj >> lg;
        int pix   = jj & (hw - 1);
        int yy = pix >> lw;
        int xx = pix & (w - 1);
        const float* Fp = F + ((size_t)plane << lg);
        float v = Fp[pix];
        bool yok = (yy < w - 1);
        bool xok = (xx < w - 1);
        float inv_e = 0.5f / (16.0f * (float)(w - 1) * (float)w);
        float inv_d = 0.5f / (16.0f * (float)(w - 1) * (float)(w - 1));
        if (yok) { float d = Fp[pix + w] - v;          acc += charb_fast(d) * inv_e; }
        if (xok) { float d = Fp[pix + 1] - v;          acc += charb_fast(d) * inv_e; }
        if (yok && xok) {
            float d  = Fp[pix + w + 1] - v;            acc += charb_fast(d)  * inv_d;
            float d2 = Fp[pix + 1] - Fp[pix + w];      acc += charb_fast(d2) * inv_d;
        }
    }
    float r = block_reduce_sum(acc);
    if (threadIdx.x == 0) {
        atomicAdd(&sums[1], r);
        __threadfence();
        unsigned old = atomicAdd((unsigned*)&sums[2], 1u);
        if (old == TAIL_BLOCKS - 1) {
            float evl = sums[0];                     // complete since previous dispatch
            float sm  = atomicAdd(&sums[1], 0.0f);   // coherent read of this dispatch's sum
            out[0] = evl + sm;
            out[1] = evl;
            out[2] = sm;
        }
    }
}

extern "C" void kernel_launch(void* const* d_in, const int* in_sizes, int n_in,
                              void* d_out, int out_size, void* d_ws, size_t ws_size,
                              hipStream_t stream) {
    const float* ev = (const float*)d_in[0];
    const float* f0 = (const float*)d_in[1];
    const float* f1 = (const float*)d_in[2];
    const float* f2 = (const float*)d_in[3];
    const float* f3 = (const float*)d_in[4];
    float* ws  = (float*)d_ws;
    float* out = (float*)d_out;

    prep_kernel<<<BB, 1024, 0, stream>>>(ev, ws);
    digest_kernel<<<(BB * NN + 255) / 256, 256, 0, stream>>>(ev, ws);
    scatter_kernel<<<8 * 56, 1024, 0, stream>>>(f0, f1, f2, f3, ws);
    tail_kernel<<<TAIL_BLOCKS, 256, 0, stream>>>(f0, f1, f2, f3, ws + OFF_SUMS, out);
}

// Round 8
// 144.473 us; speedup vs baseline: 9.6263x; 1.5124x over previous
//
#include <hip/hip_runtime.h>
#include <math.h>
#include <limits.h>

#define BB 8
#define NN 50000
#define NCH 8
#define CHSZ 6250                      // NN/NCH
#define EPSF 1.1920928955078125e-07f   // float32 machine eps
#define CEPS2 1.0e-6f                  // CHAR_EPS^2
#define QS   4194304.0f                // 2^22 fixed-point quantum for packed num
#define QINV (1.0f/4194304.0f)

// ---- ws layout (float offsets; total ~3.5 MB) ----
// params: 8*32 floats = [a, invP0..3, tf_pos, tf_neg, tl_pos, tl_neg, tmax, G0..3, ...]
#define OFF_PARAMS 0
#define OFF_SUMS   256      // [0] evloss [1] smooth [2] counter (zeroed in finalize)
#define OFF_MINMAX 384      // int[8][8][4] per (batch,chunk): minp,maxp,minn,maxn
#define OFF_HIST   640      // u32[8][8][512]
#define OFF_COFF   33408    // u32[8][8][512] chunk write-offsets
#define OFF_PRE    66176    // u32[8][513] (stride 516) exclusive prefix per bin, [512]=NN
#define OFF_DG     70336    // uint2[8][50000] sorted digest {f32 tb; x|y<<8|pol<<16}

#define SC_BLOCKS 448
#define SM_BLOCKS 256
#define TOT_BLOCKS (SC_BLOCKS + SM_BLOCKS)
#define SMOOTH_N  1392640

__device__ __forceinline__ unsigned long long encq(float v) {
    return (unsigned long long)((1LL << 40) + (long long)__float2int_rn(v * QS));
}

// valid on thread 0 only
__device__ __forceinline__ float block_reduce_sum(float v) {
    __shared__ float sm_[16];
    int lane = threadIdx.x & 63, wid = threadIdx.x >> 6;
    #pragma unroll
    for (int o = 32; o > 0; o >>= 1) v += __shfl_down(v, o);
    if (lane == 0) sm_[wid] = v;
    __syncthreads();
    float r = 0.0f;
    if (threadIdx.x == 0) {
        int nw = blockDim.x >> 6;
        for (int i = 0; i < nw; ++i) r += sm_[i];
    }
    __syncthreads();
    return r;
}

// valid on thread 0 only; safe for repeated calls
__device__ __forceinline__ float block_reduce_max(float v) {
    __shared__ float smx[16];
    int lane = threadIdx.x & 63, wid = threadIdx.x >> 6;
    #pragma unroll
    for (int o = 32; o > 0; o >>= 1) v = fmaxf(v, __shfl_down(v, o));
    if (lane == 0) smx[wid] = v;
    __syncthreads();
    float r = 0.0f;
    if (threadIdx.x == 0) {
        int nw = blockDim.x >> 6;
        for (int i = 0; i < nw; ++i) r = fmaxf(r, smx[i]);
    }
    __syncthreads();
    return r;
}

// pass 1: per (batch, chunk) histogram of (pol,y) + min/max event index per polarity
__global__ __launch_bounds__(1024) void stats_kernel(const float* __restrict__ ev, float* __restrict__ ws) {
    int b = blockIdx.x >> 3, c = blockIdx.x & 7;
    const float* ey = ev + ((size_t)b * 4 + 1) * NN;
    const float* ep = ev + ((size_t)b * 4 + 3) * NN;
    __shared__ unsigned hist[512];
    __shared__ int s0[1024], s1[1024], s2[1024], s3[1024];
    for (int i = threadIdx.x; i < 512; i += 1024) hist[i] = 0;
    __syncthreads();
    int minp = INT_MAX, maxp = -1, minn = INT_MAX, maxn = -1;
    int start = c * CHSZ, end = start + CHSZ;
    for (int n = start + threadIdx.x; n < end; n += 1024) {
        int yv = (int)ey[n];
        bool pos = (ep[n] == 1.0f);
        atomicAdd(&hist[(pos ? 0 : 256) + yv], 1u);
        if (pos) { minp = min(minp, n); maxp = max(maxp, n); }
        else     { minn = min(minn, n); maxn = max(maxn, n); }
    }
    int tid = threadIdx.x;
    s0[tid] = minp; s1[tid] = maxp; s2[tid] = minn; s3[tid] = maxn;
    __syncthreads();
    for (int o = 512; o > 0; o >>= 1) {
        if (tid < o) {
            s0[tid] = min(s0[tid], s0[tid + o]);
            s1[tid] = max(s1[tid], s1[tid + o]);
            s2[tid] = min(s2[tid], s2[tid + o]);
            s3[tid] = max(s3[tid], s3[tid + o]);
        }
        __syncthreads();
    }
    unsigned* gh = (unsigned*)(ws + OFF_HIST) + ((b << 3) + c) * 512;
    for (int i = tid; i < 512; i += 1024) gh[i] = hist[i];
    if (tid == 0) {
        int* mm = (int*)(ws + OFF_MINMAX) + ((b << 3) + c) * 4;
        mm[0] = s0[0]; mm[1] = s1[0]; mm[2] = s2[0]; mm[3] = s3[0];
    }
}

// pass 2 (one block per batch): params + guards + bin prefix + chunk offsets
__global__ __launch_bounds__(1024) void finalize_kernel(const float* __restrict__ ev,
                            const float* __restrict__ f0, const float* __restrict__ f1,
                            const float* __restrict__ f2, const float* __restrict__ f3,
                            float* __restrict__ ws) {
    int b = blockIdx.x, tid = threadIdx.x;
    float* pp = ws + OFF_PARAMS + b * 32;
    __shared__ float smaxfy[4];

    // max |fy| per scale (flow planes are small; strided reduce)
    const float* fys[4] = { f0 + ((size_t)b * 2 + 1) * 1024,  f1 + ((size_t)b * 2 + 1) * 4096,
                            f2 + ((size_t)b * 2 + 1) * 16384, f3 + ((size_t)b * 2 + 1) * 65536 };
    const int fhw[4] = { 1024, 4096, 16384, 65536 };
    for (int s = 0; s < 4; ++s) {
        float m = 0.0f;
        for (int i = tid; i < fhw[s]; i += 1024) m = fmaxf(m, fabsf(fys[s][i]));
        float r = block_reduce_max(m);
        if (tid == 0) smaxfy[s] = r;
    }
    __syncthreads();

    if (tid == 0) {
        const int* mm = (const int*)(ws + OFF_MINMAX) + (b << 3) * 4;
        int mp = INT_MAX, xp = -1, mn = INT_MAX, xn = -1;
        for (int c = 0; c < 8; ++c) {
            mp = min(mp, mm[c * 4 + 0]); xp = max(xp, mm[c * 4 + 1]);
            mn = min(mn, mm[c * 4 + 2]); xn = max(xn, mm[c * 4 + 3]);
        }
        if (xp < 0) { mp = 0; xp = NN - 1; }   // argmax(all-false)==0 semantics
        if (xn < 0) { mn = 0; xn = NN - 1; }
        const float* t = ev + ((size_t)b * 4 + 2) * NN;
        float a = t[0], tlast = t[NN - 1];
        float d0 = tlast - a + EPSF;
        float P  = d0;
        float r  = (tlast - a) / d0;
        pp[0] = a;
        pp[1] = 1.0f / P;
        for (int i = 1; i < 4; ++i) {
            float d = r + EPSF;
            P *= d;
            r  = r / d;
            pp[1 + i] = 1.0f / P;
        }
        pp[5] = t[mp];   // first pos
        pp[6] = t[mn];   // first neg
        pp[7] = t[xp];   // last pos
        pp[8] = t[xn];   // last neg
        float tmax = tlast - a;
        pp[9] = tmax;
        // guard G per scale: max |t_| * max|fy|, t_ linear in tb -> extremes at tb in {0, tmax}
        for (int s = 0; s < 4; ++s) {
            float invP = pp[1 + s];
            float T = 0.0f;
            for (int pol = 0; pol < 2; ++pol) {
                float tf = pp[5 + pol] - a, tl = pp[7 + pol] - a;
                float b0 = tl * invP + EPSF;    // sgn 0
                float b1 = tf * invP - EPSF;    // sgn 1
                T = fmaxf(T, fmaxf(fabsf(b0), fabsf(b0 - tmax * invP)));
                T = fmaxf(T, fmaxf(fabsf(b1), fabsf(b1 - tmax * invP)));
            }
            pp[10 + s] = (float)((int)ceilf(T * smaxfy[s]) + 1);
        }
        if (b == 0) { ws[OFF_SUMS] = 0.0f; ws[OFF_SUMS + 1] = 0.0f; ws[OFF_SUMS + 2] = 0.0f; }
    }
    __syncthreads();

    // bin prefix (512 bins) + per-chunk offsets
    __shared__ unsigned tot[512], bincnt[512];
    if (tid < 512) {
        unsigned run = 0;
        for (int c = 0; c < 8; ++c) {
            const unsigned* gh = (const unsigned*)(ws + OFF_HIST) + ((b << 3) + c) * 512;
            unsigned* gc = (unsigned*)(ws + OFF_COFF) + ((b << 3) + c) * 512;
            gc[tid] = run;
            run += gh[tid];
        }
        bincnt[tid] = run;
        tot[tid] = run;
    }
    __syncthreads();
    for (int o = 1; o < 512; o <<= 1) {
        unsigned v = 0;
        if (tid < 512 && tid >= o) v = tot[tid - o];
        __syncthreads();
        if (tid < 512 && tid >= o) tot[tid] += v;
        __syncthreads();
    }
    if (tid < 512) {
        unsigned Pex = tot[tid] - bincnt[tid];
        unsigned* gp = (unsigned*)(ws + OFF_PRE) + b * 516;
        gp[tid] = Pex;
        if (tid == 511) gp[512] = tot[511];   // == NN
        for (int c = 0; c < 8; ++c) {
            unsigned* gc = (unsigned*)(ws + OFF_COFF) + ((b << 3) + c) * 512;
            gc[tid] += Pex;
        }
    }
}

// pass 3: write digest sorted by (pol, y)
__global__ __launch_bounds__(1024) void sortwrite_kernel(const float* __restrict__ ev, float* __restrict__ ws) {
    int b = blockIdx.x >> 3, c = blockIdx.x & 7;
    const float* ex = ev + (size_t)b * 4 * NN;
    const float* ey = ex + NN;
    const float* et = ex + 2 * NN;
    const float* ep = ex + 3 * NN;
    __shared__ unsigned cur[512];
    const unsigned* gc = (const unsigned*)(ws + OFF_COFF) + ((b << 3) + c) * 512;
    for (int i = threadIdx.x; i < 512; i += 1024) cur[i] = gc[i];
    __syncthreads();
    float a = et[0];
    uint2* dg = (uint2*)(ws + OFF_DG) + (size_t)b * NN;
    int start = c * CHSZ, end = start + CHSZ;
    for (int n = start + threadIdx.x; n < end; n += 1024) {
        float x = ex[n], y = ey[n], tt = et[n], p = ep[n];
        int yv = (int)y;
        int pol = (p == 1.0f) ? 0 : 1;
        unsigned idx = atomicAdd(&cur[(pol << 8) + yv], 1u);
        uint2 d;
        d.x = __float_as_uint(tt - a);
        d.y = (unsigned)(int)x | ((unsigned)yv << 8) | ((unsigned)pol << 16);
        dg[idx] = d;
    }
}

__device__ __forceinline__ float charb_fast(float d) {
    return __expf(0.45f * __logf(d * d + CEPS2));
}

// mega: blocks [0,448) scatter (LDS-tile + fused reduce), [448,704) smoothness;
// last block (device counter) writes the 3 outputs.
__global__ __launch_bounds__(1024) void mega_kernel(const float* __restrict__ f0,
                            const float* __restrict__ f1, const float* __restrict__ f2,
                            const float* __restrict__ f3, float* __restrict__ ws,
                            float* __restrict__ out) {
    float* sums = ws + OFF_SUMS;
    float r = 0.0f;
    int slot;
    if (blockIdx.x < SC_BLOCKS) {
        slot = 0;
        __shared__ unsigned long long lds[8192];   // 64 KB max
        int b    = blockIdx.x & 7;
        int tile = blockIdx.x >> 3;
        int scale, c4, lo, nrows, w, sh;
        const float* fl;
        if (tile < 4)       { scale = 0; c4 = tile;      lo = 0;             nrows = 32; w = 32;  sh = 3; fl = f0; }
        else if (tile < 8)  { scale = 1; c4 = tile - 4;  lo = 0;             nrows = 64; w = 64;  sh = 2; fl = f1; }
        else if (tile < 24) { int g = tile - 8;  scale = 2; c4 = g >> 2; lo = (g & 3) * 32; nrows = 32; w = 128; sh = 1; fl = f2; }
        else                { int g = tile - 24; scale = 3; c4 = g >> 3; lo = (g & 7) * 32; nrows = 32; w = 256; sh = 0; fl = f3; }
        int pol = c4 >> 1, sgn = c4 & 1;
        int hw = w * w;
        int ncell = nrows * w;

        for (int i = threadIdx.x; i < ncell / 2; i += 1024)
            ((ulonglong2*)lds)[i] = make_ulonglong2(0ULL, 0ULL);
        __syncthreads();

        const float* pp = ws + OFF_PARAMS + b * 32;
        float a    = pp[0];
        float invP = pp[1 + scale];
        float edge = (sgn == 0) ? (pp[7 + pol] - a) : (pp[5 + pol] - a);
        float base_t = edge * invP + ((sgn == 0) ? EPSF : -EPSF);
        fl += (size_t)b * 2 * hw;

        // scan range from sorted digest: rows [lo-G, lo+nrows-1+G] at this scale
        int ylo = 0, yhi = 255;
        if (scale >= 2) {
            int G = (int)pp[10 + scale];
            ylo = (lo - G) << sh;
            yhi = ((lo + nrows - 1 + G) << sh) + ((1 << sh) - 1);
            ylo = max(ylo, 0); yhi = min(yhi, 255);
        }
        const unsigned* gp = (const unsigned*)(ws + OFF_PRE) + b * 516 + (pol << 8);
        int r0 = (int)gp[ylo], r1 = (int)gp[yhi + 1];

        const uint2* dg = ((const uint2*)(ws + OFF_DG)) + (size_t)b * NN;
        float wm1 = (float)(w - 1);

        for (int n = r0 + threadIdx.x; n < r1; n += 1024) {
            uint2 d = dg[n];
            float tb = __uint_as_float(d.x);
            int xi = (int)(d.y & 255u) >> sh;
            int yi = (int)((d.y >> 8) & 255u) >> sh;
            float fx = fl[yi * w + xi];
            float fy = fl[hw + yi * w + xi];
            float t_ = base_t - tb * invP;
            float x_ = fminf(fmaxf((float)xi + t_ * fx, 0.0f), wm1);
            float y_ = fminf(fmaxf((float)yi + t_ * fy, 0.0f), wm1);
            float x0 = floorf(x_), x1 = ceilf(x_);
            float y0 = floorf(y_), y1 = ceilf(y_);
            float x0r = 1.0f - (x_ - x0), x1r = 1.0f - (x1 - x_);
            float y0r = 1.0f - (y_ - y0), y1r = 1.0f - (y1 - y_);
            int ix0 = (int)x0, ix1 = (int)x1;
            int rr0 = (int)y0 - lo, rr1 = (int)y1 - lo;
            if (rr0 >= 0 && rr0 < nrows) {
                atomicAdd(&lds[rr0 * w + ix0], encq((x0r * y0r + EPSF) * t_));
                atomicAdd(&lds[rr0 * w + ix1], encq((x1r * y0r + EPSF) * t_));
            }
            if (rr1 >= 0 && rr1 < nrows) {
                atomicAdd(&lds[rr1 * w + ix0], encq((x0r * y1r + EPSF) * t_));
                atomicAdd(&lds[rr1 * w + ix1], encq((x1r * y1r + EPSF) * t_));
            }
        }
        __syncthreads();

        float acc = 0.0f;
        for (int i = threadIdx.x; i < ncell; i += 1024) {
            unsigned long long A = lds[i];
            if (!A) continue;
            unsigned long long cnt = (A + (1ULL << 39)) >> 40;
            long long sq = (long long)(A - (cnt << 40));
            float num = (float)sq * QINV;
            float v = num / ((float)cnt + EPSF);
            acc += v * v;
        }
        r = block_reduce_sum(acc);
    } else {
        slot = 1;
        int bi = blockIdx.x - SC_BLOCKS;
        int stride = SM_BLOCKS * 1024;
        float acc = 0.0f;
        for (int j = bi * 1024 + threadIdx.x; j < SMOOTH_N; j += stride) {
            const float* F; int jj, lg, lw;
            if (j < 16384)       { F = f0; jj = j;          lg = 10; lw = 5; }
            else if (j < 81920)  { F = f1; jj = j - 16384;  lg = 12; lw = 6; }
            else if (j < 344064) { F = f2; jj = j - 81920;  lg = 14; lw = 7; }
            else                 { F = f3; jj = j - 344064; lg = 16; lw = 8; }
            int hw = 1 << lg;
            int w  = 1 << lw;
            int plane = jj >> lg;
            int pix   = jj & (hw - 1);
            int yy = pix >> lw;
            int xx = pix & (w - 1);
            const float* Fp = F + ((size_t)plane << lg);
            float v = Fp[pix];
            bool yok = (yy < w - 1);
            bool xok = (xx < w - 1);
            float inv_e = 0.5f / (16.0f * (float)(w - 1) * (float)w);
            float inv_d = 0.5f / (16.0f * (float)(w - 1) * (float)(w - 1));
            if (yok) { float d = Fp[pix + w] - v;          acc += charb_fast(d) * inv_e; }
            if (xok) { float d = Fp[pix + 1] - v;          acc += charb_fast(d) * inv_e; }
            if (yok && xok) {
                float d  = Fp[pix + w + 1] - v;            acc += charb_fast(d)  * inv_d;
                float d2 = Fp[pix + 1] - Fp[pix + w];      acc += charb_fast(d2) * inv_d;
            }
        }
        r = block_reduce_sum(acc);
    }
    if (threadIdx.x == 0) {
        atomicAdd(&sums[slot], r);
        __threadfence();
        unsigned old = atomicAdd((unsigned*)&sums[2], 1u);
        if (old == TOT_BLOCKS - 1) {
            float evl = atomicAdd(&sums[0], 0.0f);   // coherent reads
            float sm  = atomicAdd(&sums[1], 0.0f);
            out[0] = evl + sm;
            out[1] = evl;
            out[2] = sm;
        }
    }
}

extern "C" void kernel_launch(void* const* d_in, const int* in_sizes, int n_in,
                              void* d_out, int out_size, void* d_ws, size_t ws_size,
                              hipStream_t stream) {
    const float* ev = (const float*)d_in[0];
    const float* f0 = (const float*)d_in[1];
    const float* f1 = (const float*)d_in[2];
    const float* f2 = (const float*)d_in[3];
    const float* f3 = (const float*)d_in[4];
    float* ws  = (float*)d_ws;
    float* out = (float*)d_out;

    stats_kernel<<<64, 1024, 0, stream>>>(ev, ws);
    finalize_kernel<<<BB, 1024, 0, stream>>>(ev, f0, f1, f2, f3, ws);
    sortwrite_kernel<<<64, 1024, 0, stream>>>(ev, ws);
    mega_kernel<<<TOT_BLOCKS, 1024, 0, stream>>>(f0, f1, f2, f3, ws, out);
}